// Round 10
// baseline (3851.823 us; speedup 1.0000x reference)
//
#include <hip/hip_runtime.h>

// InverseRecurrentLayer: 512-step scan  state = tanh(h_t + state@Wt + bias),
// Wt alternating every 64 steps between inv(W)=W^T (orthogonal) and W.
// v10 = v9 + x0-init fix. v9's failure (absmax 0.143) was NOT the dataflow sync:
// the x0 init wrote only 64 of the block's 128 columns; the other 64 kept the
// 0xAA ws-poison (fp16 ~= -0.052) -> deterministic drift. Now 2 col-pairs/thread.
//  - 32 blocks x 512 thr: 4 row-groups x 8 col-splits (128 cols/block).
//  - wave = one 16-col n-tile, FULL K=1024: wf[32] -> no kg-reduce, 2 syncs/step.
//  - per-producer dataflow flags (64B spaced): wave w polls ONLY producer w
//    (lane 0, 1 load/round); own-slice wave skips (own stores drained at the
//    end-of-step __syncthreads). Depth-2 ping-pong safe: a block's slot write
//    follows gates proving all 8 group members finished step t-1 (= all reads
//    of the to-be-overwritten state t-1 completed).
//  - h = inputs@R prepass into d_out (own slice), hv prefetched at step top.

#define NTHR 512
#define TSTEPS 512
#define NBLK 32

typedef __attribute__((ext_vector_type(4))) float f32x4;
typedef __attribute__((ext_vector_type(8))) _Float16 f16x8;
typedef unsigned long long u64;
typedef unsigned int u32;

union pk2 { _Float16 h[2]; u32 u; };

__device__ __forceinline__ f32x4 mfma16(f16x8 a, f16x8 b, f32x4 c){
  return __builtin_amdgcn_mfma_f32_16x16x32_f16(a, b, c, 0, 0, 0);
}

__global__ __launch_bounds__(NTHR, 2) void irl_scan(
    const float* __restrict__ inputs, const float* __restrict__ R,
    const float* __restrict__ W, const float* __restrict__ bias,
    const float* __restrict__ x0, float* __restrict__ out,
    unsigned short* __restrict__ st,   // 2 x [64][1024] fp16 state (ping-pong)
    unsigned* __restrict__ flags)      // (grp*8+p)*16 u32 stride (64B apart)
{
  __shared__ char  alds[16 * 2048];        // state tile [16 rows][1024 k] fp16, swizzled
  __shared__ float red[2][4][2][16][16];   // prepass kg-reduce only (16KB)

  const int tid = threadIdx.x;
  const int w   = tid >> 6;            // 8 waves
  const int l   = tid & 63;
  const int lr  = l & 15;              // A row / D col
  const int lg  = l >> 4;              // k-subgroup / D row-subgroup
  const int cblk = blockIdx.x & 7;     // col-split (producer id within group)
  const int grp  = blockIdx.x >> 3;    // row-group
  const int col0 = cblk << 7;          // 128 unit-columns per block
  const int r0   = grp << 4;           // 16 batch rows per block
  const int u    = col0 + w*16 + lr;   // scan: this wave's output column
  const float bias_u = bias[u];
  unsigned* myf   = flags + (((grp << 3) + cblk) << 4);
  unsigned* pollf = flags + (((grp << 3) + w) << 4);

  // ---- state[0] <- x0 : 16 rows x 64 col-pairs (2 pairs/thread — v9 bug fix) ----
  {
    const int row = tid >> 5, cp = tid & 31;
    #pragma unroll
    for (int s = 0; s < 2; ++s){
      const int c = cp + s*32;               // col-pair 0..63
      pk2 p;
      p.h[0] = (_Float16)x0[col0 + 2*c];
      p.h[1] = (_Float16)x0[col0 + 2*c + 1];
      __hip_atomic_store((u32*)st + (size_t)(r0 + row)*512 + (col0 >> 1) + c, p.u,
                         __ATOMIC_RELAXED, __HIP_MEMORY_SCOPE_AGENT);
    }
  }
  __syncthreads();                      // drains vmcnt: x0 slice visible
  if (tid == 0)
    __hip_atomic_store(myf, 1u, __ATOMIC_RELAXED, __HIP_MEMORY_SCOPE_AGENT);

  // ---- PREPASS: h = inputs@R into d_out (own 16x128 slice, all t) ----
  {
    const int kg = w >> 2;              // K-half of F=512
    const int n  = w & 3;               // 32-col subgroup
    const int u0 = col0 + n*32 + lr, u1 = u0 + 16;
    f16x8 rf0[8], rf1[8];
    #pragma unroll
    for (int i = 0; i < 8; ++i){
      const int k = kg*256 + i*32 + lg*8;
      f16x8 t0, t1;
      #pragma unroll
      for (int j = 0; j < 8; ++j){
        t0[j] = (_Float16)R[(size_t)(k + j)*1024 + u0];
        t1[j] = (_Float16)R[(size_t)(k + j)*1024 + u1];
      }
      rf0[i] = t0; rf1[i] = t1;
    }
    for (int t = 0; t < TSTEPS; ++t){
      f32x4 a0 = {0.f,0.f,0.f,0.f}, a1 = a0;
      const float* base = inputs + ((size_t)(r0 + lr)*512 + (size_t)t)*512 + kg*256 + lg*8;
      #pragma unroll
      for (int i = 0; i < 8; ++i){
        float4 xa = *(const float4*)(base + i*32);
        float4 xb = *(const float4*)(base + i*32 + 4);
        f16x8 a;
        a[0]=(_Float16)xa.x; a[1]=(_Float16)xa.y; a[2]=(_Float16)xa.z; a[3]=(_Float16)xa.w;
        a[4]=(_Float16)xb.x; a[5]=(_Float16)xb.y; a[6]=(_Float16)xb.z; a[7]=(_Float16)xb.w;
        a0 = mfma16(a, rf0[i], a0);
        a1 = mfma16(a, rf1[i], a1);
      }
      const int par = t & 1;
      if (kg == 1){
        #pragma unroll
        for (int j = 0; j < 4; ++j){
          red[par][n][0][lg*4 + j][lr] = a0[j];
          red[par][n][1][lg*4 + j][lr] = a1[j];
        }
      }
      __syncthreads();
      if (kg == 0){
        #pragma unroll
        for (int j = 0; j < 4; ++j){
          const int row = lg*4 + j;
          out[(size_t)t*65536 + (size_t)(r0 + row)*1024 + u0] = a0[j] + red[par][n][0][row][lr];
          out[(size_t)t*65536 + (size_t)(r0 + row)*1024 + u1] = a1[j] + red[par][n][1][row][lr];
        }
      }
    }
  }

  // ---- SCAN ----
  unsigned cur = 0;
  int pp = -1;
  f16x8 wf[32];                         // current phase, full K=1024: 128 VGPR
  for (int t = 0; t < TSTEPS; ++t){
    const int ph = (t >> 6) & 1;        // 1 -> W, 0 -> inv(W)=W^T
    if (ph != pp){
      pp = ph;
      if (ph){
        #pragma unroll
        for (int i = 0; i < 32; ++i){
          const int k = i*32 + lg*8;
          f16x8 tv;
          #pragma unroll
          for (int j = 0; j < 8; ++j)
            tv[j] = (_Float16)W[(size_t)(k + j)*1024 + u];   // W: B[n][k]=W[k][u]
          wf[i] = tv;
        }
      } else {
        #pragma unroll
        for (int i = 0; i < 32; ++i){
          const int k = i*32 + lg*8;
          f16x8 tv;
          #pragma unroll
          for (int j = 0; j < 8; ++j)
            tv[j] = (_Float16)W[(size_t)u*1024 + k + j];     // W^T: B[n][k]=W[u][k]
          wf[i] = tv;
        }
      }
    }

    // h prefetch for this step (own prepass slice; completes under stage)
    float hv[4];
    #pragma unroll
    for (int j = 0; j < 4; ++j)
      hv[j] = out[(size_t)t*65536 + (size_t)(r0 + lg*4 + j)*1024 + u];

    // gate: wave w waits for producer w (skip self: own stores drained already)
    if (w != cblk){
      const unsigned gen = (unsigned)(t + 1);
      for (;;){
        unsigned v = 0xffffffffu;
        if (l == 0)
          v = __hip_atomic_load(pollf, __ATOMIC_RELAXED, __HIP_MEMORY_SCOPE_AGENT);
        if (__all((int)(v >= gen))) break;
        __builtin_amdgcn_s_sleep(1);
      }
    }
    asm volatile("" ::: "memory");      // loads below must not hoist above the gate

    // stage producer w's 16x128 slice: 8 u64 atomic loads, then LDS writes
    const u64* sb = (const u64*)(st + ((size_t)cur << 16));
    u64 q[8];
    #pragma unroll
    for (int i = 0; i < 8; ++i){
      const int row = i*2 + (l >> 5), cq = l & 31;
      q[i] = __hip_atomic_load(sb + (size_t)(r0 + row)*256 + w*32 + cq,
                               __ATOMIC_RELAXED, __HIP_MEMORY_SCOPE_AGENT);
    }
    #pragma unroll
    for (int i = 0; i < 8; ++i){
      const int row = i*2 + (l >> 5), kc = w*32 + (l & 31);
      *(u64*)(alds + row*2048 + ((kc*8) ^ ((row & 7) << 4))) = q[i];
    }
    __syncthreads();

    // recurrent GEMM: 32 MFMAs, full K
    f32x4 acc = {0.f, 0.f, 0.f, 0.f};
    #pragma unroll
    for (int i = 0; i < 32; ++i){
      f16x8 a = *(const f16x8*)(alds + lr*2048 + ((i*64 + lg*16) ^ ((lr & 7) << 4)));
      acc = mfma16(a, wf[i], acc);
    }

    // epilogue: every wave owns its n-tile; no cross-wave reduce
    unsigned* nb = (u32*)(st + ((size_t)(cur ^ 1u) << 16));
    #pragma unroll
    for (int j = 0; j < 4; ++j){
      const int row = lg*4 + j;
      const float v = tanhf(acc[j] + hv[j] + bias_u);
      __builtin_nontemporal_store(v, out + (size_t)t*65536 + (size_t)(r0 + row)*1024 + u);
      pk2 me; me.h[0] = (_Float16)v; me.h[1] = (_Float16)0.f;
      const u32 other = (u32)__shfl_xor((int)me.u, 1);
      if (!(lr & 1))
        __hip_atomic_store(nb + (size_t)(r0 + row)*512 + (u >> 1),
                           (me.u & 0xffffu) | (other << 16),
                           __ATOMIC_RELAXED, __HIP_MEMORY_SCOPE_AGENT);
    }

    cur ^= 1u;
    if (t < TSTEPS - 1){
      __syncthreads();                  // all waves' state stores drained (vmcnt)
      if (tid == 0)
        __hip_atomic_store(myf, (unsigned)(t + 2), __ATOMIC_RELAXED, __HIP_MEMORY_SCOPE_AGENT);
    }
  }
}

extern "C" void kernel_launch(void* const* d_in, const int* in_sizes, int n_in,
                              void* d_out, int out_size, void* d_ws, size_t ws_size,
                              hipStream_t stream){
  (void)in_sizes; (void)n_in; (void)out_size; (void)ws_size;
  const float* inputs = (const float*)d_in[0];   // [64,512,512] f32
  const float* R      = (const float*)d_in[1];   // [512,1024]  f32
  const float* W      = (const float*)d_in[2];   // [1024,1024] f32
  const float* bias   = (const float*)d_in[3];   // [1024]      f32
  const float* x0     = (const float*)d_in[4];   // [1024]      f32
  float* out = (float*)d_out;                    // [512,64,1024] f32 (h, then states)

  char* ws = (char*)d_ws;
  unsigned* flags = (unsigned*)ws;                       // 4KB (32 flags x 64B)
  unsigned short* st = (unsigned short*)(ws + 4096);     // 2 x 64x1024 fp16

  hipMemsetAsync(flags, 0, 4096, stream);
  hipLaunchKernelGGL(irl_scan, dim3(NBLK), dim3(NTHR), 0, stream,
                     inputs, R, W, bias, x0, out, st, flags);
}

// Round 11
// 2234.433 us; speedup vs baseline: 1.7238x; 1.7238x over previous
//
#include <hip/hip_runtime.h>

// InverseRecurrentLayer v11 — three dispatches:
//  (1) cvt_wr: W -> Wa (=W[u][k]) / Wb (=W^T[u][k]) / Rt (=R^T[u][f]) as fp16 in ws.
//  (2) h_prepass: h = inputs@R + bias into d_out (f32), all CUs (~60-100us).
//  (3) irl_scan: 32 blocks x 512 thr, dataflow flags (v10 topology), BUT the
//      state exchange uses inline-asm batched sc1 dwordx4 loads / dwordx2 stores
//      with ONE waitcnt — killing the ~0.8us-per-op serialized __hip_atomic chain
//      that set the 6.5us/step floor in r3-r10 (step time tracked atomic count).

#define TSTEPS 512

typedef __attribute__((ext_vector_type(4))) float f32x4;
typedef __attribute__((ext_vector_type(8))) _Float16 f16x8;
typedef unsigned long long u64;
typedef unsigned int u32;

union pk2 { _Float16 h[2]; u32 u; };

__device__ __forceinline__ f32x4 mfma16(f16x8 a, f16x8 b, f32x4 c){
  return __builtin_amdgcn_mfma_f32_16x16x32_f16(a, b, c, 0, 0, 0);
}
// device-coherent (MALL) batched access: same visibility as relaxed agent atomics,
// but no per-op waitcnt — caller drains once with waitvm0().
__device__ __forceinline__ f32x4 gload_sc1_b128(const void* p){
  f32x4 r;
  asm volatile("global_load_dwordx4 %0, %1, off sc1" : "=v"(r) : "v"(p) : "memory");
  return r;
}
__device__ __forceinline__ void gstore_sc1_b64(void* p, u64 d){
  asm volatile("global_store_dwordx2 %0, %1, off sc1" :: "v"(p), "v"(d) : "memory");
}
__device__ __forceinline__ void waitvm0(){
  asm volatile("s_waitcnt vmcnt(0)" ::: "memory");
}

// ---------------- (1) weight convert ----------------
__global__ void cvt_wr(const float* __restrict__ W, const float* __restrict__ R,
                       _Float16* __restrict__ Wa, _Float16* __restrict__ Wb,
                       _Float16* __restrict__ Rt){
  const int n  = gridDim.x * blockDim.x;
  const int id = blockIdx.x * blockDim.x + threadIdx.x;
  for (int i = id; i < 1024*1024; i += n){
    const float v = W[i];
    Wa[i] = (_Float16)v;                              // Wa[u][k] = W[u][k]
    const int k = i >> 10, u = i & 1023;
    Wb[u*1024 + k] = (_Float16)v;                     // Wb[u][k] = W[k][u]
  }
  for (int i = id; i < 512*1024; i += n){
    const int f = i >> 10, u = i & 1023;
    Rt[u*512 + f] = (_Float16)R[i];                   // Rt[u][f] = R[f][u]
  }
}

// ---------------- (2) h prepass: out[t][b][u] = sum_f in[b][t][f] R[f][u] + bias ----------------
__global__ __launch_bounds__(512, 2) void h_prepass(
    const float* __restrict__ inputs, const _Float16* __restrict__ Rt,
    const float* __restrict__ bias, float* __restrict__ out){
  const int t  = blockIdx.x;
  const int w  = threadIdx.x >> 6, l = threadIdx.x & 63;
  const int lr = l & 15, lg = l >> 4;
  const int b0 = (w >> 1) * 16;        // 16 batch rows
  const int c0 = (w & 1) * 512;        // 512 unit cols

  f32x4 acc[32];
  #pragma unroll
  for (int n = 0; n < 32; ++n) acc[n] = (f32x4){0.f,0.f,0.f,0.f};

  for (int kc = 0; kc < 16; ++kc){
    const float* ip = inputs + (size_t)(b0 + lr)*262144 + (size_t)t*512 + kc*32 + lg*8;
    float4 xa = *(const float4*)ip, xb = *(const float4*)(ip + 4);
    f16x8 a;
    a[0]=(_Float16)xa.x; a[1]=(_Float16)xa.y; a[2]=(_Float16)xa.z; a[3]=(_Float16)xa.w;
    a[4]=(_Float16)xb.x; a[5]=(_Float16)xb.y; a[6]=(_Float16)xb.z; a[7]=(_Float16)xb.w;
    const _Float16* rp = Rt + (size_t)(c0 + lr)*512 + kc*32 + lg*8;
    #pragma unroll
    for (int n = 0; n < 32; ++n){
      f16x8 b = *(const f16x8*)(rp + (size_t)n*(16*512));
      acc[n] = mfma16(a, b, acc[n]);
    }
  }
  #pragma unroll
  for (int n = 0; n < 32; ++n){
    const int u = c0 + n*16 + lr;
    const float bu = bias[u];
    #pragma unroll
    for (int j = 0; j < 4; ++j)
      out[(size_t)t*65536 + (size_t)(b0 + lg*4 + j)*1024 + u] = acc[n][j] + bu;
  }
}

// ---------------- (3) scan ----------------
__global__ __launch_bounds__(512, 2) void irl_scan(
    const _Float16* __restrict__ Wa, const _Float16* __restrict__ Wb,
    const float* __restrict__ x0, float* __restrict__ out,
    unsigned short* __restrict__ st, unsigned* __restrict__ flags)
{
  __shared__ char alds[16 * 2048];     // row-group state [16 rows][1024 k] fp16, swizzled

  const int tid = threadIdx.x;
  const int w   = tid >> 6;            // 8 waves: n-tile owner AND producer-w stager
  const int l   = tid & 63;
  const int lr  = l & 15;
  const int lg  = l >> 4;
  const int cblk = blockIdx.x & 7;     // col-split (producer id in group)
  const int grp  = blockIdx.x >> 3;    // row-group
  const int col0 = cblk << 7;          // 128 cols per block
  const int r0   = grp << 4;           // 16 rows per block
  const int u    = col0 + w*16 + lr;
  unsigned* myf   = flags + (((grp << 3) + cblk) << 4);
  unsigned* pollf = flags + (((grp << 3) + w) << 4);

  // state[0] <- x0 : 16 rows x 128 cols (2 col-pairs/thread), sc1 u32 stores
  {
    const int row = tid >> 5, cp = tid & 31;
    #pragma unroll
    for (int s = 0; s < 2; ++s){
      const int c = cp + s*32;
      pk2 p;
      p.h[0] = (_Float16)x0[col0 + 2*c];
      p.h[1] = (_Float16)x0[col0 + 2*c + 1];
      __hip_atomic_store((u32*)st + (size_t)(r0 + row)*512 + (col0 >> 1) + c, p.u,
                         __ATOMIC_RELAXED, __HIP_MEMORY_SCOPE_AGENT);
    }
  }
  __syncthreads();
  if (tid == 0)
    __hip_atomic_store(myf, 1u, __ATOMIC_RELAXED, __HIP_MEMORY_SCOPE_AGENT);

  unsigned cur = 0;
  int pp = -1;
  f16x8 wf[32];                        // current phase, full K=1024
  for (int t = 0; t < TSTEPS; ++t){
    const int ph = (t >> 6) & 1;       // 1 -> W (Wb), 0 -> W^T (Wa)
    if (ph != pp){
      pp = ph;
      const _Float16* Wsel = ph ? Wb : Wa;
      #pragma unroll
      for (int i = 0; i < 32; ++i)
        wf[i] = *(const f16x8*)(Wsel + (size_t)u*1024 + i*32 + lg*8);
    }

    // h prefetch (prepass output, plain cached loads; completes under gate/stage)
    float hv[4];
    #pragma unroll
    for (int j = 0; j < 4; ++j)
      hv[j] = out[(size_t)t*65536 + (size_t)(r0 + lg*4 + j)*1024 + u];

    // gate: wave w waits for producer w's flag (skip self)
    if (w != cblk){
      const unsigned gen = (unsigned)(t + 1);
      for (;;){
        unsigned v = 0xffffffffu;
        if (l == 0)
          v = __hip_atomic_load(pollf, __ATOMIC_RELAXED, __HIP_MEMORY_SCOPE_AGENT);
        if (__all((int)(v >= gen))) break;
        __builtin_amdgcn_s_sleep(1);
      }
    }
    asm volatile("" ::: "memory");

    // stage producer w's 16x128 slice: 4 batched sc1 dwordx4 loads, ONE waitcnt
    const char* stB = (const char*)st + ((size_t)cur << 17);
    f32x4 q[4];
    #pragma unroll
    for (int i = 0; i < 4; ++i){
      const int row = i*4 + lg;
      q[i] = gload_sc1_b128(stB + (size_t)(r0 + row)*2048 + w*256 + lr*16);
    }
    waitvm0();
    #pragma unroll
    for (int i = 0; i < 4; ++i){
      const int row = i*4 + lg;
      *(f32x4*)(alds + row*2048 + ((w*256 + lr*16) ^ ((row & 7) << 4))) = q[i];
    }
    __syncthreads();

    // recurrent GEMM: 32 MFMAs, 2 independent chains
    f32x4 ac0 = {0.f,0.f,0.f,0.f}, ac1 = ac0;
    #pragma unroll
    for (int i = 0; i < 32; i += 2){
      f16x8 a0 = *(const f16x8*)(alds + lr*2048 + ((i*64 + lg*16) ^ ((lr & 7) << 4)));
      f16x8 a1 = *(const f16x8*)(alds + lr*2048 + (((i+1)*64 + lg*16) ^ ((lr & 7) << 4)));
      ac0 = mfma16(a0, wf[i], ac0);
      ac1 = mfma16(a1, wf[i+1], ac1);
    }
    const f32x4 acc = ac0 + ac1;

    // epilogue: tanh -> out (nontemporal) + packed sc1 state stores (4 cols/store)
    char* nbB = (char*)st + ((size_t)(cur ^ 1u) << 17);
    #pragma unroll
    for (int j = 0; j < 4; ++j){
      const int row = lg*4 + j;
      const float v = tanhf(acc[j] + hv[j]);
      __builtin_nontemporal_store(v, out + (size_t)t*65536 + (size_t)(r0 + row)*1024 + u);
      pk2 me; me.h[0] = (_Float16)v; me.h[1] = (_Float16)0.f;
      const u32 two = (me.u & 0xffffu) | ((u32)__shfl_xor((int)me.u, 1) << 16);
      const u64 four = (u64)two | ((u64)(u32)__shfl_xor((int)two, 2) << 32);
      if (!(lr & 3))
        gstore_sc1_b64(nbB + (size_t)(r0 + row)*2048 + (size_t)(u & ~3)*2, four);
    }

    cur ^= 1u;
    if (t < TSTEPS - 1){
      waitvm0();                       // own state stores at MALL before flag
      __syncthreads();                 // whole block done
      if (tid == 0)
        __hip_atomic_store(myf, (unsigned)(t + 2), __ATOMIC_RELAXED, __HIP_MEMORY_SCOPE_AGENT);
    }
  }
}

extern "C" void kernel_launch(void* const* d_in, const int* in_sizes, int n_in,
                              void* d_out, int out_size, void* d_ws, size_t ws_size,
                              hipStream_t stream){
  (void)in_sizes; (void)n_in; (void)out_size; (void)ws_size;
  const float* inputs = (const float*)d_in[0];   // [64,512,512] f32
  const float* R      = (const float*)d_in[1];   // [512,1024]  f32
  const float* W      = (const float*)d_in[2];   // [1024,1024] f32
  const float* bias   = (const float*)d_in[3];   // [1024]      f32
  const float* x0     = (const float*)d_in[4];   // [1024]      f32
  float* out = (float*)d_out;                    // [512,64,1024] f32 (h, then states)

  char* ws = (char*)d_ws;
  unsigned* flags     = (unsigned*)ws;                    // 4 KB
  unsigned short* st  = (unsigned short*)(ws + 4096);     // 2 x 64x1024 fp16 (256 KB)
  _Float16* Rt = (_Float16*)(ws + (512<<10));             // 1 MB  @ 0.5 MB
  _Float16* Wa = (_Float16*)(ws + (2u<<20));              // 2 MB  @ 2 MB
  _Float16* Wb = (_Float16*)(ws + (4u<<20));              // 2 MB  @ 4 MB

  hipMemsetAsync(flags, 0, 4096, stream);
  hipLaunchKernelGGL(cvt_wr,    dim3(1024), dim3(256), 0, stream, W, R, Wa, Wb, Rt);
  hipLaunchKernelGGL(h_prepass, dim3(512),  dim3(512), 0, stream, inputs, Rt, bias, out);
  hipLaunchKernelGGL(irl_scan,  dim3(32),   dim3(512), 0, stream, Wa, Wb, x0, out, st, flags);
}